// Round 1
// baseline (718.422 us; speedup 1.0000x reference)
//
#include <hip/hip_runtime.h>

typedef __bf16 bf16x8 __attribute__((ext_vector_type(8)));
typedef float f32x16 __attribute__((ext_vector_type(16)));

#define K_DIM 256

// ---------------------------------------------------------------------------
// Prep 1: weight-norm a (rows x 256) fp32 matrix. Optionally write:
//   dstb: bf16, k-chunk-major layout [k>>3][row][8]  (MFMA staging layout)
//   dstf: fp32, row-major (for the cond path, keeps gamma/beta accurate)
// One wave per row.
// ---------------------------------------------------------------------------
__global__ void wn_kernel(const float* __restrict__ v, const float* __restrict__ gv,
                          __bf16* __restrict__ dstb, float* __restrict__ dstf) {
  const int r = blockIdx.x;
  const int l = threadIdx.x;  // 64 threads
  const float* vr = v + (size_t)r * K_DIM;
  float4 p = *reinterpret_cast<const float4*>(vr + l * 4);
  float ss = p.x * p.x + p.y * p.y + p.z * p.z + p.w * p.w;
#pragma unroll
  for (int m = 1; m <= 32; m <<= 1) ss += __shfl_xor(ss, m, 64);
  const float sc = gv[r] * rsqrtf(ss);
  const float a0 = p.x * sc, a1 = p.y * sc, a2 = p.z * sc, a3 = p.w * sc;
  if (dstf != nullptr) {
    float4 o; o.x = a0; o.y = a1; o.z = a2; o.w = a3;
    *reinterpret_cast<float4*>(dstf + (size_t)r * K_DIM + l * 4) = o;
  }
  if (dstb != nullptr) {
    const int rows = gridDim.x;
    // k = 4l..4l+3 -> kchunk = l>>1, intra-chunk j = (l&1)*4
    __bf16* d = dstb + ((size_t)(l >> 1) * rows + r) * 8 + (l & 1) * 4;
    d[0] = (__bf16)a0; d[1] = (__bf16)a1; d[2] = (__bf16)a2; d[3] = (__bf16)a3;
  }
}

// ---------------------------------------------------------------------------
// Prep 2: gbuf[g][0:256]  = gamma = cond @ wnc^T + b_cond + 1   (cols 0:256)
//         gbuf[g][256:512]= beta  = cond @ wnc^T + b_cond       (cols 256:512)
// One block per group g, 256 threads, 2 outputs per thread.
// ---------------------------------------------------------------------------
__global__ void gb_kernel(const float* __restrict__ cond, const float* __restrict__ wncf,
                          const float* __restrict__ bc, float* __restrict__ gbuf) {
  const int gidx = blockIdx.x;
  const int t = threadIdx.x;  // 256
  __shared__ float c[256];
  c[t] = cond[(size_t)gidx * 256 + t];
  __syncthreads();
#pragma unroll
  for (int h = 0; h < 2; ++h) {
    const int o = (h << 8) + t;
    const float* wr = wncf + (size_t)o * 256;
    float s = 0.0f;
#pragma unroll 8
    for (int k = 0; k < 256; k += 4) {
      const float4 w4 = *reinterpret_cast<const float4*>(wr + k);
      s += c[k] * w4.x + c[k + 1] * w4.y + c[k + 2] * w4.z + c[k + 3] * w4.w;
    }
    gbuf[(size_t)gidx * 512 + o] = s + bc[o] + (h == 0 ? 1.0f : 0.0f);
  }
}

// ---------------------------------------------------------------------------
// Main fused kernel: 64 rows per block, 128 threads (2 waves x 32 rows).
//   stage1: s1 = x @ W1^T (A-frags straight from global fp32 x, cvt to bf16)
//   LN + FiLM(batch_ids) + relu -> Abuf (LDS, k-chunk-major)
//   stage2: relu(h @ W2^T + b2)  -> Abuf
//   stage3: h2 @ W3^T + b3 -> out (two 256-col halves)
// Weight K-tiles staged into Wbuf with global_load_lds (contiguous memcpy).
// ---------------------------------------------------------------------------
__global__ __launch_bounds__(128, 2) void fused_kernel(
    const float* __restrict__ x, const int* __restrict__ bids,
    const __bf16* __restrict__ W1t, const __bf16* __restrict__ W2t,
    const __bf16* __restrict__ W3t, const float* __restrict__ gbuf,
    const float* __restrict__ b2, const float* __restrict__ b3,
    float* __restrict__ out, const int n) {
  __shared__ __bf16 Abuf[32 * 64 * 8];  // 32 KiB: h tile, [kc][row][8]
  __shared__ __bf16 Wbuf[4 * 256 * 8];  // 16 KiB: weight K-tile, [kc][out][8]

  const int t = threadIdx.x;
  const int lane = t & 63;
  const int wave = t >> 6;      // 0..1
  const int nlo = lane & 31;    // MFMA m / n lane index
  const int g = lane >> 5;      // MFMA k-group
  const int mbase = wave << 5;  // this wave's row base within the 64-row tile
  const int R = blockIdx.x << 6;

  f32x16 zero;
#pragma unroll
  for (int e = 0; e < 16; ++e) zero[e] = 0.0f;

  f32x16 acc[8];

  // stage a 16KB weight K-tile [kc 0..3][out 0..255][8] into Wbuf.
  auto stage_w = [&](const __bf16* wsrc, int kt, int outr, int outbase) {
#pragma unroll
    for (int it = 0; it < 8; ++it) {
      const int cid = (((wave << 3) + it) << 6) + lane;  // chunk id 0..1023
      const int kc = cid >> 8;
      const int outl = cid & 255;
      const __bf16* gp = wsrc + ((size_t)((kt * 4 + kc) * outr + outbase + outl) << 3);
      __builtin_amdgcn_global_load_lds(
          (__attribute__((address_space(1))) void*)gp,
          (__attribute__((address_space(3))) void*)(&Wbuf[((wave << 3) + it) << 9]),
          16, 0, 0);
    }
  };

  // ---------------- stage 1: s1 = x @ W1^T ----------------
#pragma unroll
  for (int nt = 0; nt < 8; ++nt) acc[nt] = zero;
  {
    int row = R + mbase + nlo;
    if (row >= n) row = n - 1;
    const float* xrow = x + (size_t)row * K_DIM;
    for (int kt = 0; kt < 8; ++kt) {
      __syncthreads();
      stage_w(W1t, kt, 256, 0);
      __syncthreads();
#pragma unroll
      for (int ks = 0; ks < 2; ++ks) {
        const int k0 = kt * 32 + ks * 16 + g * 8;
        const float4 p = *reinterpret_cast<const float4*>(xrow + k0);
        const float4 q = *reinterpret_cast<const float4*>(xrow + k0 + 4);
        bf16x8 a;
        a[0] = (__bf16)p.x; a[1] = (__bf16)p.y; a[2] = (__bf16)p.z; a[3] = (__bf16)p.w;
        a[4] = (__bf16)q.x; a[5] = (__bf16)q.y; a[6] = (__bf16)q.z; a[7] = (__bf16)q.w;
#pragma unroll
        for (int nt = 0; nt < 8; ++nt) {
          const bf16x8 b = *reinterpret_cast<const bf16x8*>(
              &Wbuf[((((ks << 1) + g) << 8) + (nt << 5) + nlo) << 3]);
          acc[nt] = __builtin_amdgcn_mfma_f32_32x32x16_bf16(a, b, acc[nt], 0, 0, 0);
        }
      }
    }
  }

  // ---------------- layernorm + FiLM + relu -> Abuf ----------------
  {
    float mu[16], rs[16];
#pragma unroll
    for (int reg = 0; reg < 16; ++reg) {
      float s = 0.0f, q = 0.0f;
#pragma unroll
      for (int nt = 0; nt < 8; ++nt) {
        const float v = acc[nt][reg];
        s += v; q += v * v;
      }
#pragma unroll
      for (int m = 1; m <= 16; m <<= 1) {  // reduce over the 32-lane half-wave
        s += __shfl_xor(s, m, 64);
        q += __shfl_xor(q, m, 64);
      }
      const float mean = s * (1.0f / 256.0f);
      const float var = q * (1.0f / 256.0f) - mean * mean;
      mu[reg] = mean;
      rs[reg] = rsqrtf(var + 1e-5f);
    }
#pragma unroll
    for (int reg = 0; reg < 16; ++reg) {
      const int rl = (reg & 3) + ((reg >> 2) << 3) + (g << 2);  // C-layout row 0..31
      int rglob = R + mbase + rl;
      if (rglob >= n) rglob = n - 1;
      const int bid = bids[rglob];
      const float* grow = gbuf + ((size_t)bid << 9);
#pragma unroll
      for (int nt = 0; nt < 8; ++nt) {
        const int col = (nt << 5) + nlo;
        float v = (acc[nt][reg] - mu[reg]) * rs[reg];
        v = v * grow[col] + grow[256 + col];
        v = v > 0.0f ? v : 0.0f;
        Abuf[((((col >> 3) << 6) + mbase + rl) << 3) + (col & 7)] = (__bf16)v;
      }
    }
  }

  // ---------------- stage 2: relu(h @ W2^T + b2) -> Abuf ----------------
#pragma unroll
  for (int nt = 0; nt < 8; ++nt) acc[nt] = zero;
  for (int kt = 0; kt < 8; ++kt) {
    __syncthreads();
    stage_w(W2t, kt, 256, 0);
    __syncthreads();
#pragma unroll
    for (int ks = 0; ks < 2; ++ks) {
      const int kc = kt * 4 + ks * 2 + g;
      const bf16x8 a = *reinterpret_cast<const bf16x8*>(
          &Abuf[((kc << 6) + mbase + nlo) << 3]);
#pragma unroll
      for (int nt = 0; nt < 8; ++nt) {
        const bf16x8 b = *reinterpret_cast<const bf16x8*>(
            &Wbuf[((((ks << 1) + g) << 8) + (nt << 5) + nlo) << 3]);
        acc[nt] = __builtin_amdgcn_mfma_f32_32x32x16_bf16(a, b, acc[nt], 0, 0, 0);
      }
    }
  }
  {
    float b2v[8];
#pragma unroll
    for (int nt = 0; nt < 8; ++nt) b2v[nt] = b2[(nt << 5) + nlo];
#pragma unroll
    for (int reg = 0; reg < 16; ++reg) {
      const int rl = (reg & 3) + ((reg >> 2) << 3) + (g << 2);
#pragma unroll
      for (int nt = 0; nt < 8; ++nt) {
        const int col = (nt << 5) + nlo;
        float v = acc[nt][reg] + b2v[nt];
        v = v > 0.0f ? v : 0.0f;
        Abuf[((((col >> 3) << 6) + mbase + rl) << 3) + (col & 7)] = (__bf16)v;
      }
    }
  }

  // ---------------- stage 3: out = h2 @ W3^T + b3 (two halves) ----------------
  for (int half = 0; half < 2; ++half) {
#pragma unroll
    for (int nt = 0; nt < 8; ++nt) acc[nt] = zero;
    for (int kt = 0; kt < 8; ++kt) {
      __syncthreads();
      stage_w(W3t, kt, 512, half << 8);
      __syncthreads();
#pragma unroll
      for (int ks = 0; ks < 2; ++ks) {
        const int kc = kt * 4 + ks * 2 + g;
        const bf16x8 a = *reinterpret_cast<const bf16x8*>(
            &Abuf[((kc << 6) + mbase + nlo) << 3]);
#pragma unroll
        for (int nt = 0; nt < 8; ++nt) {
          const bf16x8 b = *reinterpret_cast<const bf16x8*>(
              &Wbuf[((((ks << 1) + g) << 8) + (nt << 5) + nlo) << 3]);
          acc[nt] = __builtin_amdgcn_mfma_f32_32x32x16_bf16(a, b, acc[nt], 0, 0, 0);
        }
      }
    }
    float b3v[8];
#pragma unroll
    for (int nt = 0; nt < 8; ++nt) b3v[nt] = b3[(half << 8) + (nt << 5) + nlo];
#pragma unroll
    for (int reg = 0; reg < 16; ++reg) {
      const int rl = (reg & 3) + ((reg >> 2) << 3) + (g << 2);
      const int rglob = R + mbase + rl;
      if (rglob < n) {
        float* orow = out + (size_t)rglob * 512 + (half << 8);
#pragma unroll
        for (int nt = 0; nt < 8; ++nt) orow[(nt << 5) + nlo] = acc[nt][reg] + b3v[nt];
      }
    }
  }
}

extern "C" void kernel_launch(void* const* d_in, const int* in_sizes, int n_in,
                              void* d_out, int out_size, void* d_ws, size_t ws_size,
                              hipStream_t stream) {
  const float* x      = (const float*)d_in[0];
  const float* cond   = (const float*)d_in[1];
  const int*   bids   = (const int*)d_in[2];
  const float* v_cond = (const float*)d_in[3];
  const float* g_cond = (const float*)d_in[4];
  const float* b_cond = (const float*)d_in[5];
  const float* v1     = (const float*)d_in[6];
  const float* g1     = (const float*)d_in[7];
  const float* v2     = (const float*)d_in[8];
  const float* g2     = (const float*)d_in[9];
  const float* b2     = (const float*)d_in[10];
  const float* v3     = (const float*)d_in[11];
  const float* g3     = (const float*)d_in[12];
  const float* b3     = (const float*)d_in[13];
  float* out = (float*)d_out;
  const int n = in_sizes[0] / K_DIM;

  // workspace layout
  char* ws = (char*)d_ws;
  __bf16* W1t = (__bf16*)ws;               // 256x256 bf16, k-chunk-major (128 KB)
  __bf16* W2t = W1t + 65536;               // 128 KB
  __bf16* W3t = W2t + 65536;               // 512x256 bf16 (256 KB)
  float* wncf = (float*)(W3t + 131072);    // 512x256 fp32 normalized v_cond (512 KB)
  float* gbuf = wncf + 131072;             // 256x512 fp32 gamma|beta (512 KB)

  wn_kernel<<<256, 64, 0, stream>>>(v1, g1, W1t, nullptr);
  wn_kernel<<<256, 64, 0, stream>>>(v2, g2, W2t, nullptr);
  wn_kernel<<<512, 64, 0, stream>>>(v3, g3, W3t, nullptr);
  wn_kernel<<<512, 64, 0, stream>>>(v_cond, g_cond, nullptr, wncf);
  gb_kernel<<<256, 256, 0, stream>>>(cond, wncf, b_cond, gbuf);

  const int nb = (n + 63) / 64;
  fused_kernel<<<nb, 128, 0, stream>>>(x, bids, W1t, W2t, W3t, gbuf, b2, b3, out, n);
}